// Round 7
// baseline (1445.588 us; speedup 1.0000x reference)
//
#include <hip/hip_runtime.h>
#include <hip/hip_fp16.h>

#define N_NODES 100000
#define N_EDGES 1200000
#define GRAPHS 128
#define EPSBN 1e-5f
#define NSHARD 8
#define SH_NODES 12500   // N_NODES / NSHARD exact
#define NSUB 8           // sub-cursors per bucket (contention spreading)
#define CAP_SUB 24576    // capacity per (bucket,sub) region; mean 18750, sigma ~136

// ---------------- phase 1: edge partition into dst-range buckets + out-degree ----------------
// Each edge appended once, packed (d<<32)|s, into bucket d/12500 via wave-aggregated
// ballot compaction: one returning atomic per wave per bucket, contiguous (coalesced) writes.
// Separates the 9.6MB edge STREAM from the later SCATTER so the scatter's working set
// can stay L2-resident in k_scat.

__global__ __launch_bounds__(256) void k_part(const int* __restrict__ src,
                                              const int* __restrict__ dst,
                                              int* __restrict__ deg,
                                              int* __restrict__ cur,
                                              long long* __restrict__ ebuf) {
    int t = threadIdx.x;
    int lane = t & 63;
    int gw = (blockIdx.x * 4 + (t >> 6)) & (NSUB - 1);   // this wave's sub-cursor
    for (int e = blockIdx.x * 256 + t; e < N_EDGES; e += gridDim.x * 256) {
        int s = src[e], d = dst[e];
        atomicAdd(&deg[s], 1);
        int b = d / SH_NODES;
        long long pack = ((long long)d << 32) | (unsigned)s;
#pragma unroll
        for (int bb = 0; bb < NSHARD; bb++) {
            unsigned long long mask = __ballot(b == bb);
            if (mask) {
                int cnt = __popcll(mask);
                int leader = __ffsll((long long)mask) - 1;
                int base = 0;
                if (lane == leader) base = atomicAdd(&cur[bb * NSUB + gw], cnt);
                base = __shfl(base, leader, 64);
                if (b == bb) {
                    int off = __popcll(mask & ((1ULL << lane) - 1));
                    if (base + off < CAP_SUB)   // defensive; never triggers on uniform data
                        ebuf[(bb * NSUB + gw) * CAP_SUB + base + off] = pack;
                }
            }
        }
    }
}

// ---------------- phase 2: per-shard scatter into CSR (L2-resident slice) ----------------
// shard = blockIdx&7 aligns each shard's blocks to one XCD (round-robin heuristic;
// correctness mapping-independent). Only this shard's ~1.6MB bucket is streamed, so the
// 3.2MB ecsr slice + 50KB cnt slice stay L2-resident -> write-backs near dirty-line floor.

__global__ __launch_bounds__(256) void k_scat(const long long* __restrict__ ebuf,
                                              const int* __restrict__ cur,
                                              int* __restrict__ cnt,
                                              int* __restrict__ ecsr) {
    int shard = blockIdx.x & (NSHARD - 1);
    int bpos = blockIdx.x >> 3;            // 0..63 (grid 512)
    int t = threadIdx.x;
    for (int sub = 0; sub < NSUB; sub++) {
        int n = cur[shard * NSUB + sub];
        if (n > CAP_SUB) n = CAP_SUB;
        const long long* base = ebuf + (shard * NSUB + sub) * CAP_SUB;
        for (int i = bpos * 256 + t; i < n; i += 64 * 256) {
            long long pack = base[i];
            int d = (int)(pack >> 32);
            int s = (int)(pack & 0xffffffffLL);
            int p = atomicAdd(&cnt[d], 1);
            ecsr[(d << 6) + p] = s;
        }
    }
}

__global__ __launch_bounds__(256) void k_dis(const int* __restrict__ deg,
                                             float* __restrict__ dis) {
    int i = blockIdx.x * 256 + threadIdx.x;
    if (i < N_NODES) dis[i] = rsqrtf((float)deg[i] + 1.0f);   // +1 self-loop
}

// ---------------- sigma[d] = dis[d] * (sum_in dis[s] + dis[d]) — layer-invariant ----------------

__global__ __launch_bounds__(256) void k_sigma(const float* __restrict__ dis,
                                               const int* __restrict__ cnt,
                                               const int* __restrict__ ecsr,
                                               float* __restrict__ sigma) {
    int lane = threadIdx.x & 63;
    int wid = threadIdx.x >> 6;
    for (int node = blockIdx.x * 4 + wid; node < N_NODES; node += gridDim.x * 4) {
        int m = cnt[node];
        int sraw = ecsr[(node << 6) + lane];
        float dd = dis[node];
        int sL = (lane < m) ? sraw : 0;
        float v = (lane < m) ? dis[sL] : 0.f;
#pragma unroll
        for (int d = 1; d <= 32; d <<= 1) v += __shfl_xor(v, d, 64);
        if (lane == 0) sigma[node] = dd * (v + dd);
    }
}

// ---------------- BN stats over x: float4 loads, LDS reduce ----------------

__global__ __launch_bounds__(256) void k_stats(const float* __restrict__ x,
                                               float* __restrict__ sums) {
    const float4* x4 = (const float4*)x;
    int t = threadIdx.x;
    int q = t & 15, rg = t >> 4;
    float4 s = {0.f, 0.f, 0.f, 0.f}, s2 = {0.f, 0.f, 0.f, 0.f};
    for (int r = blockIdx.x * 16 + rg; r < N_NODES; r += gridDim.x * 16) {
        float4 v = x4[r * 16 + q];
        s.x += v.x; s.y += v.y; s.z += v.z; s.w += v.w;
        s2.x += v.x * v.x; s2.y += v.y * v.y; s2.z += v.z * v.z; s2.w += v.w * v.w;
    }
    __shared__ float red[2][16][64];
    red[0][rg][q * 4 + 0] = s.x;  red[0][rg][q * 4 + 1] = s.y;
    red[0][rg][q * 4 + 2] = s.z;  red[0][rg][q * 4 + 3] = s.w;
    red[1][rg][q * 4 + 0] = s2.x; red[1][rg][q * 4 + 1] = s2.y;
    red[1][rg][q * 4 + 2] = s2.z; red[1][rg][q * 4 + 3] = s2.w;
    __syncthreads();
    if (t < 64) {
        float a = 0.f, b = 0.f;
#pragma unroll
        for (int k = 0; k < 16; k++) { a += red[0][k][t]; b += red[1][k][t]; }
        atomicAdd(&sums[t], a);
        atomicAdd(&sums[64 + t], b);
    }
}

// ---------------- fold BN into GEMM: W' = diag(a)W, b' = c@W (+bias) ----------------

__global__ __launch_bounds__(256) void k_fold(const float* __restrict__ sums, const float* __restrict__ g,
                       const float* __restrict__ b, const float* __restrict__ W,
                       const float* __restrict__ bias_in, int has_bias,
                       float* __restrict__ Wout, float* __restrict__ bout) {
    __shared__ float a[64], cc[64];
    int t = threadIdx.x;
    if (t < 64) {
        float mu = sums[t] * (1.0f / N_NODES);
        float var = sums[64 + t] * (1.0f / N_NODES) - mu * mu;
        float av = g[t] * rsqrtf(var + EPSBN);
        a[t] = av;
        cc[t] = b[t] - mu * av;
    }
    __syncthreads();
    for (int i = t; i < 4096; i += 256) Wout[i] = a[i >> 6] * W[i];
    if (t < 64) {
        float acc = has_bias ? bias_in[t] : 0.0f;
        for (int k = 0; k < 64; k++) acc += cc[k] * W[k * 64 + t];
        bout[t] = acc;
    }
}

// ---------------- feature GEMM: u = dis * relu(X@W + bias) fp16, fused output stats ----------------
// (256,5): ~102-VGPR budget, 5 waves/SIMD target. Spill tell = FETCH/WRITE blowup.

__global__ __launch_bounds__(256, 5) void k_gemm2(const float* __restrict__ X, const float* __restrict__ W,
                        const float* __restrict__ bias, const float* __restrict__ dis,
                        __half* __restrict__ U,
                        float* __restrict__ sums, int do_stats) {
    int t = threadIdx.x;
    int j = t & 63;
    int rg = t >> 6;
    __shared__ float wlds[64][64];
    __shared__ float xs[16][64];
    for (int i = t; i < 4096; i += 256) wlds[i >> 6][i & 63] = W[i];
    float bj = bias[j];
    __syncthreads();
    float s_sum = 0.f, s_sq = 0.f;
    for (int base = blockIdx.x * 16; base < N_NODES; base += gridDim.x * 16) {
        ((float4*)xs)[t] = ((const float4*)(X + base * 64))[t];   // wave-private rows
        int r0 = rg * 4;
        float a0 = bj, a1 = bj, a2 = bj, a3 = bj;
        const float4* x0 = (const float4*)xs[r0 + 0];
        const float4* x1 = (const float4*)xs[r0 + 1];
        const float4* x2 = (const float4*)xs[r0 + 2];
        const float4* x3 = (const float4*)xs[r0 + 3];
#pragma unroll
        for (int q4 = 0; q4 < 16; q4++) {
            float w0 = wlds[q4 * 4 + 0][j], w1 = wlds[q4 * 4 + 1][j];
            float w2 = wlds[q4 * 4 + 2][j], w3 = wlds[q4 * 4 + 3][j];
            float4 v0 = x0[q4]; a0 += v0.x * w0 + v0.y * w1 + v0.z * w2 + v0.w * w3;
            float4 v1 = x1[q4]; a1 += v1.x * w0 + v1.y * w1 + v1.z * w2 + v1.w * w3;
            float4 v2 = x2[q4]; a2 += v2.x * w0 + v2.y * w1 + v2.z * w2 + v2.w * w3;
            float4 v3 = x3[q4]; a3 += v3.x * w0 + v3.y * w1 + v3.z * w2 + v3.w * w3;
        }
        a0 = fmaxf(a0, 0.f); a1 = fmaxf(a1, 0.f);
        a2 = fmaxf(a2, 0.f); a3 = fmaxf(a3, 0.f);
        int nb = base + r0;
        U[(nb + 0) * 64 + j] = __float2half_rn(a0 * dis[nb + 0]);
        U[(nb + 1) * 64 + j] = __float2half_rn(a1 * dis[nb + 1]);
        U[(nb + 2) * 64 + j] = __float2half_rn(a2 * dis[nb + 2]);
        U[(nb + 3) * 64 + j] = __float2half_rn(a3 * dis[nb + 3]);
        if (do_stats) {
            s_sum += a0 + a1 + a2 + a3;
            s_sq += a0 * a0 + a1 * a1 + a2 * a2 + a3 * a3;
        }
    }
    if (do_stats) {
        __syncthreads();
        xs[rg][j] = s_sum;
        xs[4 + rg][j] = s_sq;
        __syncthreads();
        if (t < 64) {
            atomicAdd(&sums[t], xs[0][t] + xs[1][t] + xs[2][t] + xs[3][t]);
            atomicAdd(&sums[64 + t], xs[4][t] + xs[5][t] + xs[6][t] + xs[7][t]);
        }
    }
}

// ---------------- fused agg+GEMM with in-kernel BN fold (sigma correction) ----------------

__global__ __launch_bounds__(256, 5) void k_aggemm(const __half* __restrict__ u,
                        const float* __restrict__ dis, const float* __restrict__ sigma,
                        const int* __restrict__ cnt, const int* __restrict__ ecsr,
                        const float* __restrict__ sums_in, const float* __restrict__ bng,
                        const float* __restrict__ bnb,
                        const float* __restrict__ W, const float* __restrict__ bias,
                        __half* __restrict__ uout, float* __restrict__ hout, int last,
                        float* __restrict__ sums_out, int do_stats) {
    const __half2* u2 = (const __half2*)u;
    int t = threadIdx.x;
    int j = t & 63;           // lane; also output column in GEMM phase
    int wid = t >> 6;
    int g = j >> 5, c = j & 31;
    __shared__ float wlds[64][64];
    __shared__ float xs[16][64];   // wave w owns rows 4w..4w+3 (wave-private); prologue: xs[0]=aa, xs[1]=ccs
    if (t < 64) {
        float mu = sums_in[t] * (1.0f / N_NODES);
        float var = sums_in[64 + t] * (1.0f / N_NODES) - mu * mu;
        float av = bng[t] * rsqrtf(var + EPSBN);
        xs[0][t] = av;                 // aa
        xs[1][t] = bnb[t] - mu * av;   // ccs
    }
    __syncthreads();
    for (int i = t; i < 4096; i += 256) wlds[i >> 6][i & 63] = W[i] * xs[0][i >> 6];
    float cb = 0.f;
#pragma unroll 8
    for (int q = 0; q < 64; q++) cb += xs[1][q] * W[q * 64 + j];
    float bj = bias[j];
    __syncthreads();
    float s_sum = 0.f, s_sq = 0.f;
    for (int base = blockIdx.x * 16; base < N_NODES; base += gridDim.x * 16) {
        int r0 = wid * 4;
        int nb = base + r0;
        // ---- hoisted independent loads for all 4 rows ----
        int mm[4], srw[4];
        float dvals[4], svals[4];
        __half2 selfs[4];
#pragma unroll
        for (int r = 0; r < 4; r++) {
            mm[r] = cnt[nb + r];
            srw[r] = ecsr[((nb + r) << 6) + j];
            dvals[r] = dis[nb + r];
            svals[r] = sigma[nb + r];
            selfs[r] = u2[(nb + r) * 32 + c];
        }
        // ---- phase A: aggregate 4 nodes into wave-private xs rows ----
#pragma unroll
        for (int r = 0; r < 4; r++) {
            int m = mm[r];
            int sL = (j < m) ? srw[r] : 0;
            float ax = 0.f, ay = 0.f;
#pragma unroll
            for (int k = 0; k < 8; k++) {
                int e = 2 * k + g;
                int sE = __shfl(sL, e, 64);
                float w = (e < m) ? 1.0f : 0.0f;
                float2 f = __half22float2(u2[sE * 32 + c]);
                ax += w * f.x; ay += w * f.y;
            }
            if (m > 16) {
                for (int e = 16 + g; e < m; e += 2) {
                    int sE = __shfl(sL, e, 64);
                    float2 f = __half22float2(u2[sE * 32 + c]);
                    ax += f.x; ay += f.y;
                }
            }
            ax += __shfl_xor(ax, 32, 64);
            ay += __shfl_xor(ay, 32, 64);
            if (g == 0) {
                float2 sf = __half22float2(selfs[r]);
                float dd = dvals[r];
                xs[r0 + r][2 * c + 0] = dd * (ax + sf.x);
                xs[r0 + r][2 * c + 1] = dd * (ay + sf.y);
            }
        }
        // ---- phase B: GEMM + sigma correction (wave-private LDS, W from LDS) ----
        float a0 = bj + svals[0] * cb, a1 = bj + svals[1] * cb;
        float a2 = bj + svals[2] * cb, a3 = bj + svals[3] * cb;
        const float4* x0 = (const float4*)xs[r0 + 0];
        const float4* x1 = (const float4*)xs[r0 + 1];
        const float4* x2 = (const float4*)xs[r0 + 2];
        const float4* x3 = (const float4*)xs[r0 + 3];
#pragma unroll
        for (int q4 = 0; q4 < 16; q4++) {
            float w0 = wlds[q4 * 4 + 0][j], w1 = wlds[q4 * 4 + 1][j];
            float w2 = wlds[q4 * 4 + 2][j], w3 = wlds[q4 * 4 + 3][j];
            float4 v0 = x0[q4]; a0 += v0.x * w0 + v0.y * w1 + v0.z * w2 + v0.w * w3;
            float4 v1 = x1[q4]; a1 += v1.x * w0 + v1.y * w1 + v1.z * w2 + v1.w * w3;
            float4 v2 = x2[q4]; a2 += v2.x * w0 + v2.y * w1 + v2.z * w2 + v2.w * w3;
            float4 v3 = x3[q4]; a3 += v3.x * w0 + v3.y * w1 + v3.z * w2 + v3.w * w3;
        }
        a0 = fmaxf(a0, 0.f); a1 = fmaxf(a1, 0.f);
        a2 = fmaxf(a2, 0.f); a3 = fmaxf(a3, 0.f);
        if (last) {
            hout[(nb + 0) * 64 + j] = a0;
            hout[(nb + 1) * 64 + j] = a1;
            hout[(nb + 2) * 64 + j] = a2;
            hout[(nb + 3) * 64 + j] = a3;
        } else {
            uout[(nb + 0) * 64 + j] = __float2half_rn(a0 * dvals[0]);
            uout[(nb + 1) * 64 + j] = __float2half_rn(a1 * dvals[1]);
            uout[(nb + 2) * 64 + j] = __float2half_rn(a2 * dvals[2]);
            uout[(nb + 3) * 64 + j] = __float2half_rn(a3 * dvals[3]);
        }
        if (do_stats) {
            s_sum += a0 + a1 + a2 + a3;
            s_sq += a0 * a0 + a1 * a1 + a2 * a2 + a3 * a3;
        }
    }
    if (do_stats) {
        __syncthreads();
        xs[wid][j] = s_sum;
        xs[4 + wid][j] = s_sq;
        __syncthreads();
        if (t < 64) {
            atomicAdd(&sums_out[t], xs[0][t] + xs[1][t] + xs[2][t] + xs[3][t]);
            atomicAdd(&sums_out[64 + t], xs[4][t] + xs[5][t] + xs[6][t] + xs[7][t]);
        }
    }
}

// ---------------- global_add_pool: 4 blocks per graph, atomic partials into zeroed hg ----------------

__global__ __launch_bounds__(256) void k_pool(const float* __restrict__ h, const int* __restrict__ batch,
                       float* __restrict__ hg) {
    int g = blockIdx.x >> 2, q3 = blockIdx.x & 3;
    int lo = 0, hi = N_NODES;
    while (lo < hi) { int m = (lo + hi) >> 1; if (batch[m] < g) lo = m + 1; else hi = m; }
    int start = lo;
    lo = start; hi = N_NODES;
    while (lo < hi) { int m = (lo + hi) >> 1; if (batch[m] < g + 1) lo = m + 1; else hi = m; }
    int end = lo;
    int len = end - start;
    int c0 = start + ((len * q3) >> 2);
    int c1 = start + ((len * (q3 + 1)) >> 2);
    int c = threadIdx.x & 63, rg = threadIdx.x >> 6;
    float s = 0.f;
    for (int r = c0 + rg; r < c1; r += 4) s += h[r * 64 + c];
    __shared__ float ls[4][64];
    ls[rg][c] = s;
    __syncthreads();
    if (rg == 0) atomicAdd(&hg[g * 64 + c], ls[0][c] + ls[1][c] + ls[2][c] + ls[3][c]);
}

// ---------------- tail: BN-fc stats from hg -> BN -> FC+relu -> BN -> classifier -> log_softmax ----------------

__global__ __launch_bounds__(512) void k_tail(const float* __restrict__ hg_in,
                       const float* __restrict__ g1, const float* __restrict__ b1,
                       const float* __restrict__ Wfc, const float* __restrict__ bfc,
                       const float* __restrict__ g2, const float* __restrict__ b2,
                       const float* __restrict__ Wcls, const float* __restrict__ bcls,
                       float* __restrict__ out) {
    __shared__ float hgn[8192];
    __shared__ float h2[8192];
    __shared__ float red[2][8][64];
    __shared__ float a[64], cc[64];
    __shared__ float Wc[640];
    __shared__ float logits[1280];
    __shared__ float lse[128];
    int t = threadIdx.x;
    int j = t & 63;
    int w = t >> 6;

    // BN-fc stats over the 128 pooled rows (computed in-kernel)
    {
        float su = 0.f, sq = 0.f;
#pragma unroll
        for (int gg = 0; gg < 16; gg++) {
            float v = hg_in[(w * 16 + gg) * 64 + j];
            su += v; sq += v * v;
        }
        red[0][w][j] = su; red[1][w][j] = sq;
    }
    for (int i = t; i < 640; i += 512) Wc[i] = Wcls[i];
    __syncthreads();
    if (t < 64) {
        float su = 0.f, sq = 0.f;
#pragma unroll
        for (int k = 0; k < 8; k++) { su += red[0][k][t]; sq += red[1][k][t]; }
        float mu = su * (1.f / 128.f);
        float var = sq * (1.f / 128.f) - mu * mu;
        float av = g1[t] * rsqrtf(var + EPSBN);
        a[t] = av; cc[t] = b1[t] - mu * av;
    }
    __syncthreads();
    for (int i = t; i < 8192; i += 512) hgn[i] = hg_in[i] * a[i & 63] + cc[i & 63];

    float wreg[64];
#pragma unroll
    for (int q = 0; q < 64; q++) wreg[q] = Wfc[q * 64 + j];
    float bj = bfc[j];
    __syncthreads();

    float acc[16];
#pragma unroll
    for (int r = 0; r < 16; r++) acc[r] = bj;
    const float4* hgn4 = (const float4*)hgn;
#pragma unroll
    for (int q4 = 0; q4 < 16; q4++) {
#pragma unroll
        for (int r = 0; r < 16; r++) {
            float4 hv = hgn4[(w * 16 + r) * 16 + q4];
            acc[r] += hv.x * wreg[q4 * 4 + 0] + hv.y * wreg[q4 * 4 + 1]
                    + hv.z * wreg[q4 * 4 + 2] + hv.w * wreg[q4 * 4 + 3];
        }
    }
    float s = 0.f, s2 = 0.f;
#pragma unroll
    for (int r = 0; r < 16; r++) {
        float v = fmaxf(acc[r], 0.f);
        h2[(w * 16 + r) * 64 + j] = v;
        s += v; s2 += v * v;
    }
    red[0][w][j] = s; red[1][w][j] = s2;
    __syncthreads();

    if (t < 64) {
        float su = 0.f, sq = 0.f;
#pragma unroll
        for (int k = 0; k < 8; k++) { su += red[0][k][t]; sq += red[1][k][t]; }
        float mu = su * (1.f / 128.f);
        float var = sq * (1.f / 128.f) - mu * mu;
        float av = g2[t] * rsqrtf(var + EPSBN);
        a[t] = av; cc[t] = b2[t] - mu * av;
    }
    __syncthreads();
    for (int i = t; i < 8192; i += 512) h2[i] = h2[i] * a[i & 63] + cc[i & 63];
    __syncthreads();

    for (int idx = t; idx < 1280; idx += 512) {
        int row = idx / 10, o = idx - row * 10;
        float v = bcls[o];
#pragma unroll
        for (int q = 0; q < 64; q++) v += h2[row * 64 + q] * Wc[q * 10 + o];
        logits[idx] = v;
    }
    __syncthreads();
    if (t < 128) {
        float mx = -1e30f;
#pragma unroll
        for (int o = 0; o < 10; o++) mx = fmaxf(mx, logits[t * 10 + o]);
        float se = 0.f;
#pragma unroll
        for (int o = 0; o < 10; o++) se += expf(logits[t * 10 + o] - mx);
        lse[t] = mx + logf(se);
    }
    __syncthreads();
    for (int idx = t; idx < 1280; idx += 512) out[idx] = logits[idx] - lse[idx / 10];
}

// ---------------- launcher ----------------

extern "C" void kernel_launch(void* const* d_in, const int* in_sizes, int n_in,
                              void* d_out, int out_size, void* d_ws, size_t ws_size,
                              hipStream_t stream) {
    const float* x         = (const float*)d_in[0];
    const int*   ei        = (const int*)  d_in[1];
    const int*   batch     = (const int*)  d_in[2];
    const float* bn_feat_g = (const float*)d_in[3];
    const float* bn_feat_b = (const float*)d_in[4];
    const float* W_feat    = (const float*)d_in[5];
    const float* b_feat    = (const float*)d_in[6];
    const float* conv_bn_g = (const float*)d_in[7];
    const float* conv_bn_b = (const float*)d_in[8];
    const float* conv_W    = (const float*)d_in[9];
    const float* conv_b    = (const float*)d_in[10];
    const float* bn_fc_g   = (const float*)d_in[11];
    const float* bn_fc_b   = (const float*)d_in[12];
    const float* W_fc      = (const float*)d_in[13];
    const float* b_fc      = (const float*)d_in[14];
    const float* bn_hid_g  = (const float*)d_in[15];
    const float* bn_hid_b  = (const float*)d_in[16];
    const float* W_cls     = (const float*)d_in[17];
    const float* b_cls     = (const float*)d_in[18];
    float* out = (float*)d_out;

    float* ws    = (float*)d_ws;
    float* hbuf  = ws;                          // 6,400,000 f; ebuf during build (12.6MB), h after last aggemm
    __half* u_a  = (__half*)(ws + 6400000);     // 6.4M halves
    __half* u_b  = (__half*)(ws + 9600000);     // 6.4M halves
    float* dis   = ws + 12800000;               // 100,000 f
    float* sigma = ws + 12900000;               // 100,000 f
    float* Wt    = ws + 13000000;               // 4096 f
    float* bt    = Wt + 4096;                   // 64 f
    float* hg    = bt + 64;                     // 8192 f
    float* sums  = hg + 8192;                   // 640 f (sx,s0,s1,s2 @ 0..511; cur @ 512..575)
    int*   cnt   = (int*)(sums + 640);          // 100,000 i
    int*   ecsr  = cnt + 100000;                // 6,400,000 i
    int*   deg   = (int*)u_b;                   // 100,000 i scratch; dead before u_b written
    long long* ebuf = (long long*)hbuf;         // 64*24576*8B = 12.6MB; dead before hbuf written
    int*   cur   = (int*)(sums + 512);          // 64 i (bucket sub-cursors)

    float* sx = sums;
    float* s0 = sums + 128;
    float* s1 = sums + 256;
    float* s2 = sums + 384;

    const int* srcp = ei;
    const int* dstp = ei + N_EDGES;

    // zero hg + sums(incl. cur) + cnt in one contiguous memset; deg lives in u_b scratch
    hipMemsetAsync(hg, 0, (8192 + 640 + 100000) * sizeof(float), stream);
    hipMemsetAsync(deg, 0, 100000 * sizeof(int), stream);

    // two-phase CSR build: partition -> per-shard scatter; then dis -> sigma
    k_part<<<2048, 256, 0, stream>>>(srcp, dstp, deg, cur, ebuf);
    k_scat<<<512, 256, 0, stream>>>(ebuf, cur, cnt, ecsr);
    k_dis<<<(N_NODES + 255) / 256, 256, 0, stream>>>(deg, dis);
    k_sigma<<<1024, 256, 0, stream>>>(dis, cnt, ecsr, sigma);

    // feature layer: stats on x -> fold -> GEMM+relu -> u0 (fp16, dis-scaled), stats -> s0
    k_stats<<<512, 256, 0, stream>>>(x, sx);
    k_fold<<<1, 256, 0, stream>>>(sx, bn_feat_g, bn_feat_b, W_feat, b_feat, 1, Wt, bt);
    k_gemm2<<<2048, 256, 0, stream>>>(x, Wt, bt, dis, u_a, s0, 1);

    // 3 GCN conv layers: aggemm with in-kernel BN fold + sigma correction, u double-buffered
    k_aggemm<<<2048, 256, 0, stream>>>(u_a, dis, sigma, cnt, ecsr,
                                       s0, conv_bn_g + 0, conv_bn_b + 0,
                                       conv_W + 0, conv_b + 0,
                                       u_b, nullptr, 0, s1, 1);
    k_aggemm<<<2048, 256, 0, stream>>>(u_b, dis, sigma, cnt, ecsr,
                                       s1, conv_bn_g + 64, conv_bn_b + 64,
                                       conv_W + 4096, conv_b + 64,
                                       u_a, nullptr, 0, s2, 1);
    k_aggemm<<<2048, 256, 0, stream>>>(u_a, dis, sigma, cnt, ecsr,
                                       s2, conv_bn_g + 128, conv_bn_b + 128,
                                       conv_W + 8192, conv_b + 128,
                                       nullptr, hbuf, 1, nullptr, 0);

    // pooling + tail (BN-fc stats computed inside k_tail)
    k_pool<<<4 * GRAPHS, 256, 0, stream>>>(hbuf, batch, hg);
    k_tail<<<1, 512, 0, stream>>>(hg, bn_fc_g, bn_fc_b, W_fc, b_fc,
                                  bn_hid_g, bn_hid_b, W_cls, b_cls, out);
}

// Round 8
// 564.168 us; speedup vs baseline: 2.5623x; 2.5623x over previous
//
#include <hip/hip_runtime.h>
#include <hip/hip_fp16.h>

#define N_NODES 100000
#define N_EDGES 1200000
#define GRAPHS 128
#define EPSBN 1e-5f
#define NSHARD 8
#define SH_NODES 12500   // N_NODES / NSHARD exact
#define NBLK 2048        // partition blocks
#define EPB 586          // edges per block: 2048*586 = 1,200,128 >= N_EDGES

// ---------------- build phase 1: per-block per-bucket counts + out-degree ----------------
// Wave-ballot aggregation -> 8 LDS counters -> one 8-int row per block. NO global
// returning atomics (round-7's k_part died on 150K serialized cursor atomics: 906us,
// HBM 0.8%). deg atomics (non-returning, 100K addresses) are cheap (proven in k_build).

__global__ __launch_bounds__(256) void k_cnt(const int* __restrict__ src,
                                             const int* __restrict__ dst,
                                             int* __restrict__ deg,
                                             int* __restrict__ gcnt) {
    __shared__ int lc[NSHARD];
    int t = threadIdx.x, lane = t & 63;
    if (t < NSHARD) lc[t] = 0;
    __syncthreads();
    int e0 = blockIdx.x * EPB;
    int e1 = min(e0 + EPB, N_EDGES);
    for (int e = e0 + t; e < e1; e += 256) {
        int s = src[e], d = dst[e];
        atomicAdd(&deg[s], 1);
        int b = d / SH_NODES;
#pragma unroll
        for (int bb = 0; bb < NSHARD; bb++) {
            unsigned long long mask = __ballot(b == bb);
            if (mask && lane == (__ffsll((long long)mask) - 1))
                atomicAdd(&lc[bb], __popcll(mask));
        }
    }
    __syncthreads();
    if (t < NSHARD) gcnt[t * NBLK + blockIdx.x] = lc[t];   // bucket-major
}

// ---------------- build phase 2: exclusive scan of 8x2048 counts ----------------

__global__ __launch_bounds__(256) void k_scan(const int* __restrict__ gcnt,
                                              int* __restrict__ goff) {
    __shared__ int buf[NSHARD * NBLK];
    __shared__ int part[256];
    int t = threadIdx.x;
    for (int i = t; i < NSHARD * NBLK; i += 256) buf[i] = gcnt[i];
    __syncthreads();
    int s = 0;
#pragma unroll 8
    for (int k = 0; k < 64; k++) s += buf[t * 64 + k];
    part[t] = s;
    __syncthreads();
    // Hillis-Steele inclusive scan over 256 partials
    for (int off = 1; off < 256; off <<= 1) {
        int v = (t >= off) ? part[t - off] : 0;
        __syncthreads();
        part[t] += v;
        __syncthreads();
    }
    int run = (t == 0) ? 0 : part[t - 1];
    for (int k = 0; k < 64; k++) {
        int idx = t * 64 + k;
        int c = buf[idx];
        goff[idx] = run;
        run += c;
    }
}

// ---------------- build phase 3: place edges into dense per-bucket ranges ----------------
// Block-local LDS cursors seeded from goff; one LDS atomic per wave per bucket.
// Position sets are exact (counted), so no capacity checks, no global contention.

__global__ __launch_bounds__(256) void k_place(const int* __restrict__ src,
                                               const int* __restrict__ dst,
                                               const int* __restrict__ goff,
                                               long long* __restrict__ ebuf) {
    __shared__ int lofs[NSHARD];
    int t = threadIdx.x, lane = t & 63;
    if (t < NSHARD) lofs[t] = goff[t * NBLK + blockIdx.x];
    __syncthreads();
    int e0 = blockIdx.x * EPB;
    int e1 = min(e0 + EPB, N_EDGES);
    for (int e = e0 + t; e < e1; e += 256) {
        int s = src[e], d = dst[e];
        int b = d / SH_NODES;
        long long pack = ((long long)d << 32) | (unsigned)s;
#pragma unroll
        for (int bb = 0; bb < NSHARD; bb++) {
            unsigned long long mask = __ballot(b == bb);
            if (mask) {
                int leader = __ffsll((long long)mask) - 1;
                int base = 0;
                if (lane == leader) base = atomicAdd(&lofs[bb], __popcll(mask));
                base = __shfl(base, leader, 64);
                if (b == bb) {
                    int off = __popcll(mask & ((1ULL << lane) - 1));
                    ebuf[base + off] = pack;
                }
            }
        }
    }
}

// ---------------- build phase 4: per-shard scatter into CSR (L2-resident slice) ----------------
// shard = blockIdx&7 (XCD round-robin heuristic; correctness mapping-independent).
// Streams only its dense ~1.2MB bucket; 3.2MB ecsr slice + cnt slice stay L2-resident.

__global__ __launch_bounds__(256) void k_scat(const long long* __restrict__ ebuf,
                                              const int* __restrict__ goff,
                                              int* __restrict__ cnt,
                                              int* __restrict__ ecsr) {
    int shard = blockIdx.x & (NSHARD - 1);
    int bpos = blockIdx.x >> 3;            // 0..63 (grid 512)
    int bstart = goff[shard * NBLK];
    int bend = (shard == NSHARD - 1) ? N_EDGES : goff[(shard + 1) * NBLK];
    int t = threadIdx.x;
    for (int i = bstart + bpos * 256 + t; i < bend; i += 64 * 256) {
        long long pack = ebuf[i];
        int d = (int)(pack >> 32);
        int s = (int)(pack & 0xffffffffLL);
        int p = atomicAdd(&cnt[d], 1);
        ecsr[(d << 6) + p] = s;
    }
}

__global__ __launch_bounds__(256) void k_dis(const int* __restrict__ deg,
                                             float* __restrict__ dis) {
    int i = blockIdx.x * 256 + threadIdx.x;
    if (i < N_NODES) dis[i] = rsqrtf((float)deg[i] + 1.0f);   // +1 self-loop
}

// ---------------- sigma[d] = dis[d] * (sum_in dis[s] + dis[d]) — layer-invariant ----------------

__global__ __launch_bounds__(256) void k_sigma(const float* __restrict__ dis,
                                               const int* __restrict__ cnt,
                                               const int* __restrict__ ecsr,
                                               float* __restrict__ sigma) {
    int lane = threadIdx.x & 63;
    int wid = threadIdx.x >> 6;
    for (int node = blockIdx.x * 4 + wid; node < N_NODES; node += gridDim.x * 4) {
        int m = cnt[node];
        int sraw = ecsr[(node << 6) + lane];
        float dd = dis[node];
        int sL = (lane < m) ? sraw : 0;
        float v = (lane < m) ? dis[sL] : 0.f;
#pragma unroll
        for (int d = 1; d <= 32; d <<= 1) v += __shfl_xor(v, d, 64);
        if (lane == 0) sigma[node] = dd * (v + dd);
    }
}

// ---------------- BN stats over x: float4 loads, LDS reduce ----------------

__global__ __launch_bounds__(256) void k_stats(const float* __restrict__ x,
                                               float* __restrict__ sums) {
    const float4* x4 = (const float4*)x;
    int t = threadIdx.x;
    int q = t & 15, rg = t >> 4;
    float4 s = {0.f, 0.f, 0.f, 0.f}, s2 = {0.f, 0.f, 0.f, 0.f};
    for (int r = blockIdx.x * 16 + rg; r < N_NODES; r += gridDim.x * 16) {
        float4 v = x4[r * 16 + q];
        s.x += v.x; s.y += v.y; s.z += v.z; s.w += v.w;
        s2.x += v.x * v.x; s2.y += v.y * v.y; s2.z += v.z * v.z; s2.w += v.w * v.w;
    }
    __shared__ float red[2][16][64];
    red[0][rg][q * 4 + 0] = s.x;  red[0][rg][q * 4 + 1] = s.y;
    red[0][rg][q * 4 + 2] = s.z;  red[0][rg][q * 4 + 3] = s.w;
    red[1][rg][q * 4 + 0] = s2.x; red[1][rg][q * 4 + 1] = s2.y;
    red[1][rg][q * 4 + 2] = s2.z; red[1][rg][q * 4 + 3] = s2.w;
    __syncthreads();
    if (t < 64) {
        float a = 0.f, b = 0.f;
#pragma unroll
        for (int k = 0; k < 16; k++) { a += red[0][k][t]; b += red[1][k][t]; }
        atomicAdd(&sums[t], a);
        atomicAdd(&sums[64 + t], b);
    }
}

// ---------------- fold BN into GEMM: W' = diag(a)W, b' = c@W (+bias) ----------------

__global__ __launch_bounds__(256) void k_fold(const float* __restrict__ sums, const float* __restrict__ g,
                       const float* __restrict__ b, const float* __restrict__ W,
                       const float* __restrict__ bias_in, int has_bias,
                       float* __restrict__ Wout, float* __restrict__ bout) {
    __shared__ float a[64], cc[64];
    int t = threadIdx.x;
    if (t < 64) {
        float mu = sums[t] * (1.0f / N_NODES);
        float var = sums[64 + t] * (1.0f / N_NODES) - mu * mu;
        float av = g[t] * rsqrtf(var + EPSBN);
        a[t] = av;
        cc[t] = b[t] - mu * av;
    }
    __syncthreads();
    for (int i = t; i < 4096; i += 256) Wout[i] = a[i >> 6] * W[i];
    if (t < 64) {
        float acc = has_bias ? bias_in[t] : 0.0f;
        for (int k = 0; k < 64; k++) acc += cc[k] * W[k * 64 + t];
        bout[t] = acc;
    }
}

// ---------------- feature GEMM: u = dis * relu(X@W + bias) fp16, fused output stats ----------------
// W in LDS; (256,4) = 128-VGPR budget (spill-free, measured). xs wave-private.

__global__ __launch_bounds__(256, 4) void k_gemm2(const float* __restrict__ X, const float* __restrict__ W,
                        const float* __restrict__ bias, const float* __restrict__ dis,
                        __half* __restrict__ U,
                        float* __restrict__ sums, int do_stats) {
    int t = threadIdx.x;
    int j = t & 63;
    int rg = t >> 6;
    __shared__ float wlds[64][64];
    __shared__ float xs[16][64];
    for (int i = t; i < 4096; i += 256) wlds[i >> 6][i & 63] = W[i];
    float bj = bias[j];
    __syncthreads();
    float s_sum = 0.f, s_sq = 0.f;
    for (int base = blockIdx.x * 16; base < N_NODES; base += gridDim.x * 16) {
        ((float4*)xs)[t] = ((const float4*)(X + base * 64))[t];   // wave-private rows
        int r0 = rg * 4;
        float a0 = bj, a1 = bj, a2 = bj, a3 = bj;
        const float4* x0 = (const float4*)xs[r0 + 0];
        const float4* x1 = (const float4*)xs[r0 + 1];
        const float4* x2 = (const float4*)xs[r0 + 2];
        const float4* x3 = (const float4*)xs[r0 + 3];
#pragma unroll
        for (int q4 = 0; q4 < 16; q4++) {
            float w0 = wlds[q4 * 4 + 0][j], w1 = wlds[q4 * 4 + 1][j];
            float w2 = wlds[q4 * 4 + 2][j], w3 = wlds[q4 * 4 + 3][j];
            float4 v0 = x0[q4]; a0 += v0.x * w0 + v0.y * w1 + v0.z * w2 + v0.w * w3;
            float4 v1 = x1[q4]; a1 += v1.x * w0 + v1.y * w1 + v1.z * w2 + v1.w * w3;
            float4 v2 = x2[q4]; a2 += v2.x * w0 + v2.y * w1 + v2.z * w2 + v2.w * w3;
            float4 v3 = x3[q4]; a3 += v3.x * w0 + v3.y * w1 + v3.z * w2 + v3.w * w3;
        }
        a0 = fmaxf(a0, 0.f); a1 = fmaxf(a1, 0.f);
        a2 = fmaxf(a2, 0.f); a3 = fmaxf(a3, 0.f);
        int nb = base + r0;
        U[(nb + 0) * 64 + j] = __float2half_rn(a0 * dis[nb + 0]);
        U[(nb + 1) * 64 + j] = __float2half_rn(a1 * dis[nb + 1]);
        U[(nb + 2) * 64 + j] = __float2half_rn(a2 * dis[nb + 2]);
        U[(nb + 3) * 64 + j] = __float2half_rn(a3 * dis[nb + 3]);
        if (do_stats) {
            s_sum += a0 + a1 + a2 + a3;
            s_sq += a0 * a0 + a1 * a1 + a2 * a2 + a3 * a3;
        }
    }
    if (do_stats) {
        __syncthreads();
        xs[rg][j] = s_sum;
        xs[4 + rg][j] = s_sq;
        __syncthreads();
        if (t < 64) {
            atomicAdd(&sums[t], xs[0][t] + xs[1][t] + xs[2][t] + xs[3][t]);
            atomicAdd(&sums[64 + t], xs[4][t] + xs[5][t] + xs[6][t] + xs[7][t]);
        }
    }
}

// ---------------- fused agg+GEMM with in-kernel BN fold (sigma correction) ----------------

__global__ __launch_bounds__(256, 4) void k_aggemm(const __half* __restrict__ u,
                        const float* __restrict__ dis, const float* __restrict__ sigma,
                        const int* __restrict__ cnt, const int* __restrict__ ecsr,
                        const float* __restrict__ sums_in, const float* __restrict__ bng,
                        const float* __restrict__ bnb,
                        const float* __restrict__ W, const float* __restrict__ bias,
                        __half* __restrict__ uout, float* __restrict__ hout, int last,
                        float* __restrict__ sums_out, int do_stats) {
    const __half2* u2 = (const __half2*)u;
    int t = threadIdx.x;
    int j = t & 63;           // lane; also output column in GEMM phase
    int wid = t >> 6;
    int g = j >> 5, c = j & 31;
    __shared__ float wlds[64][64];
    __shared__ float xs[16][64];   // wave w owns rows 4w..4w+3 (wave-private); prologue: xs[0]=aa, xs[1]=ccs
    if (t < 64) {
        float mu = sums_in[t] * (1.0f / N_NODES);
        float var = sums_in[64 + t] * (1.0f / N_NODES) - mu * mu;
        float av = bng[t] * rsqrtf(var + EPSBN);
        xs[0][t] = av;                 // aa
        xs[1][t] = bnb[t] - mu * av;   // ccs
    }
    __syncthreads();
    for (int i = t; i < 4096; i += 256) wlds[i >> 6][i & 63] = W[i] * xs[0][i >> 6];
    float cb = 0.f;
#pragma unroll 8
    for (int q = 0; q < 64; q++) cb += xs[1][q] * W[q * 64 + j];
    float bj = bias[j];
    __syncthreads();
    float s_sum = 0.f, s_sq = 0.f;
    for (int base = blockIdx.x * 16; base < N_NODES; base += gridDim.x * 16) {
        int r0 = wid * 4;
        int nb = base + r0;
        // ---- hoisted independent loads for all 4 rows ----
        int mm[4], srw[4];
        float dvals[4], svals[4];
        __half2 selfs[4];
#pragma unroll
        for (int r = 0; r < 4; r++) {
            mm[r] = cnt[nb + r];
            srw[r] = ecsr[((nb + r) << 6) + j];
            dvals[r] = dis[nb + r];
            svals[r] = sigma[nb + r];
            selfs[r] = u2[(nb + r) * 32 + c];
        }
        // ---- phase A: aggregate 4 nodes into wave-private xs rows ----
#pragma unroll
        for (int r = 0; r < 4; r++) {
            int m = mm[r];
            int sL = (j < m) ? srw[r] : 0;
            float ax = 0.f, ay = 0.f;
#pragma unroll
            for (int k = 0; k < 8; k++) {
                int e = 2 * k + g;
                int sE = __shfl(sL, e, 64);
                float w = (e < m) ? 1.0f : 0.0f;
                float2 f = __half22float2(u2[sE * 32 + c]);
                ax += w * f.x; ay += w * f.y;
            }
            if (m > 16) {
                for (int e = 16 + g; e < m; e += 2) {
                    int sE = __shfl(sL, e, 64);
                    float2 f = __half22float2(u2[sE * 32 + c]);
                    ax += f.x; ay += f.y;
                }
            }
            ax += __shfl_xor(ax, 32, 64);
            ay += __shfl_xor(ay, 32, 64);
            if (g == 0) {
                float2 sf = __half22float2(selfs[r]);
                float dd = dvals[r];
                xs[r0 + r][2 * c + 0] = dd * (ax + sf.x);
                xs[r0 + r][2 * c + 1] = dd * (ay + sf.y);
            }
        }
        // ---- phase B: GEMM + sigma correction (wave-private LDS, W from LDS) ----
        float a0 = bj + svals[0] * cb, a1 = bj + svals[1] * cb;
        float a2 = bj + svals[2] * cb, a3 = bj + svals[3] * cb;
        const float4* x0 = (const float4*)xs[r0 + 0];
        const float4* x1 = (const float4*)xs[r0 + 1];
        const float4* x2 = (const float4*)xs[r0 + 2];
        const float4* x3 = (const float4*)xs[r0 + 3];
#pragma unroll
        for (int q4 = 0; q4 < 16; q4++) {
            float w0 = wlds[q4 * 4 + 0][j], w1 = wlds[q4 * 4 + 1][j];
            float w2 = wlds[q4 * 4 + 2][j], w3 = wlds[q4 * 4 + 3][j];
            float4 v0 = x0[q4]; a0 += v0.x * w0 + v0.y * w1 + v0.z * w2 + v0.w * w3;
            float4 v1 = x1[q4]; a1 += v1.x * w0 + v1.y * w1 + v1.z * w2 + v1.w * w3;
            float4 v2 = x2[q4]; a2 += v2.x * w0 + v2.y * w1 + v2.z * w2 + v2.w * w3;
            float4 v3 = x3[q4]; a3 += v3.x * w0 + v3.y * w1 + v3.z * w2 + v3.w * w3;
        }
        a0 = fmaxf(a0, 0.f); a1 = fmaxf(a1, 0.f);
        a2 = fmaxf(a2, 0.f); a3 = fmaxf(a3, 0.f);
        if (last) {
            hout[(nb + 0) * 64 + j] = a0;
            hout[(nb + 1) * 64 + j] = a1;
            hout[(nb + 2) * 64 + j] = a2;
            hout[(nb + 3) * 64 + j] = a3;
        } else {
            uout[(nb + 0) * 64 + j] = __float2half_rn(a0 * dvals[0]);
            uout[(nb + 1) * 64 + j] = __float2half_rn(a1 * dvals[1]);
            uout[(nb + 2) * 64 + j] = __float2half_rn(a2 * dvals[2]);
            uout[(nb + 3) * 64 + j] = __float2half_rn(a3 * dvals[3]);
        }
        if (do_stats) {
            s_sum += a0 + a1 + a2 + a3;
            s_sq += a0 * a0 + a1 * a1 + a2 * a2 + a3 * a3;
        }
    }
    if (do_stats) {
        __syncthreads();
        xs[wid][j] = s_sum;
        xs[4 + wid][j] = s_sq;
        __syncthreads();
        if (t < 64) {
            atomicAdd(&sums_out[t], xs[0][t] + xs[1][t] + xs[2][t] + xs[3][t]);
            atomicAdd(&sums_out[64 + t], xs[4][t] + xs[5][t] + xs[6][t] + xs[7][t]);
        }
    }
}

// ---------------- global_add_pool: 4 blocks per graph, atomic partials into zeroed hg ----------------

__global__ __launch_bounds__(256) void k_pool(const float* __restrict__ h, const int* __restrict__ batch,
                       float* __restrict__ hg) {
    int g = blockIdx.x >> 2, q3 = blockIdx.x & 3;
    int lo = 0, hi = N_NODES;
    while (lo < hi) { int m = (lo + hi) >> 1; if (batch[m] < g) lo = m + 1; else hi = m; }
    int start = lo;
    lo = start; hi = N_NODES;
    while (lo < hi) { int m = (lo + hi) >> 1; if (batch[m] < g + 1) lo = m + 1; else hi = m; }
    int end = lo;
    int len = end - start;
    int c0 = start + ((len * q3) >> 2);
    int c1 = start + ((len * (q3 + 1)) >> 2);
    int c = threadIdx.x & 63, rg = threadIdx.x >> 6;
    float s = 0.f;
    for (int r = c0 + rg; r < c1; r += 4) s += h[r * 64 + c];
    __shared__ float ls[4][64];
    ls[rg][c] = s;
    __syncthreads();
    if (rg == 0) atomicAdd(&hg[g * 64 + c], ls[0][c] + ls[1][c] + ls[2][c] + ls[3][c]);
}

// ---------------- tail: BN-fc stats from hg -> BN -> FC+relu -> BN -> classifier -> log_softmax ----------------

__global__ __launch_bounds__(512) void k_tail(const float* __restrict__ hg_in,
                       const float* __restrict__ g1, const float* __restrict__ b1,
                       const float* __restrict__ Wfc, const float* __restrict__ bfc,
                       const float* __restrict__ g2, const float* __restrict__ b2,
                       const float* __restrict__ Wcls, const float* __restrict__ bcls,
                       float* __restrict__ out) {
    __shared__ float hgn[8192];
    __shared__ float h2[8192];
    __shared__ float red[2][8][64];
    __shared__ float a[64], cc[64];
    __shared__ float Wc[640];
    __shared__ float logits[1280];
    __shared__ float lse[128];
    int t = threadIdx.x;
    int j = t & 63;
    int w = t >> 6;

    // BN-fc stats over the 128 pooled rows (computed in-kernel)
    {
        float su = 0.f, sq = 0.f;
#pragma unroll
        for (int gg = 0; gg < 16; gg++) {
            float v = hg_in[(w * 16 + gg) * 64 + j];
            su += v; sq += v * v;
        }
        red[0][w][j] = su; red[1][w][j] = sq;
    }
    for (int i = t; i < 640; i += 512) Wc[i] = Wcls[i];
    __syncthreads();
    if (t < 64) {
        float su = 0.f, sq = 0.f;
#pragma unroll
        for (int k = 0; k < 8; k++) { su += red[0][k][t]; sq += red[1][k][t]; }
        float mu = su * (1.f / 128.f);
        float var = sq * (1.f / 128.f) - mu * mu;
        float av = g1[t] * rsqrtf(var + EPSBN);
        a[t] = av; cc[t] = b1[t] - mu * av;
    }
    __syncthreads();
    for (int i = t; i < 8192; i += 512) hgn[i] = hg_in[i] * a[i & 63] + cc[i & 63];

    float wreg[64];
#pragma unroll
    for (int q = 0; q < 64; q++) wreg[q] = Wfc[q * 64 + j];
    float bj = bfc[j];
    __syncthreads();

    float acc[16];
#pragma unroll
    for (int r = 0; r < 16; r++) acc[r] = bj;
    const float4* hgn4 = (const float4*)hgn;
#pragma unroll
    for (int q4 = 0; q4 < 16; q4++) {
#pragma unroll
        for (int r = 0; r < 16; r++) {
            float4 hv = hgn4[(w * 16 + r) * 16 + q4];
            acc[r] += hv.x * wreg[q4 * 4 + 0] + hv.y * wreg[q4 * 4 + 1]
                    + hv.z * wreg[q4 * 4 + 2] + hv.w * wreg[q4 * 4 + 3];
        }
    }
    float s = 0.f, s2 = 0.f;
#pragma unroll
    for (int r = 0; r < 16; r++) {
        float v = fmaxf(acc[r], 0.f);
        h2[(w * 16 + r) * 64 + j] = v;
        s += v; s2 += v * v;
    }
    red[0][w][j] = s; red[1][w][j] = s2;
    __syncthreads();

    if (t < 64) {
        float su = 0.f, sq = 0.f;
#pragma unroll
        for (int k = 0; k < 8; k++) { su += red[0][k][t]; sq += red[1][k][t]; }
        float mu = su * (1.f / 128.f);
        float var = sq * (1.f / 128.f) - mu * mu;
        float av = g2[t] * rsqrtf(var + EPSBN);
        a[t] = av; cc[t] = b2[t] - mu * av;
    }
    __syncthreads();
    for (int i = t; i < 8192; i += 512) h2[i] = h2[i] * a[i & 63] + cc[i & 63];
    __syncthreads();

    for (int idx = t; idx < 1280; idx += 512) {
        int row = idx / 10, o = idx - row * 10;
        float v = bcls[o];
#pragma unroll
        for (int q = 0; q < 64; q++) v += h2[row * 64 + q] * Wc[q * 10 + o];
        logits[idx] = v;
    }
    __syncthreads();
    if (t < 128) {
        float mx = -1e30f;
#pragma unroll
        for (int o = 0; o < 10; o++) mx = fmaxf(mx, logits[t * 10 + o]);
        float se = 0.f;
#pragma unroll
        for (int o = 0; o < 10; o++) se += expf(logits[t * 10 + o] - mx);
        lse[t] = mx + logf(se);
    }
    __syncthreads();
    for (int idx = t; idx < 1280; idx += 512) out[idx] = logits[idx] - lse[idx / 10];
}

// ---------------- launcher ----------------

extern "C" void kernel_launch(void* const* d_in, const int* in_sizes, int n_in,
                              void* d_out, int out_size, void* d_ws, size_t ws_size,
                              hipStream_t stream) {
    const float* x         = (const float*)d_in[0];
    const int*   ei        = (const int*)  d_in[1];
    const int*   batch     = (const int*)  d_in[2];
    const float* bn_feat_g = (const float*)d_in[3];
    const float* bn_feat_b = (const float*)d_in[4];
    const float* W_feat    = (const float*)d_in[5];
    const float* b_feat    = (const float*)d_in[6];
    const float* conv_bn_g = (const float*)d_in[7];
    const float* conv_bn_b = (const float*)d_in[8];
    const float* conv_W    = (const float*)d_in[9];
    const float* conv_b    = (const float*)d_in[10];
    const float* bn_fc_g   = (const float*)d_in[11];
    const float* bn_fc_b   = (const float*)d_in[12];
    const float* W_fc      = (const float*)d_in[13];
    const float* b_fc      = (const float*)d_in[14];
    const float* bn_hid_g  = (const float*)d_in[15];
    const float* bn_hid_b  = (const float*)d_in[16];
    const float* W_cls     = (const float*)d_in[17];
    const float* b_cls     = (const float*)d_in[18];
    float* out = (float*)d_out;

    float* ws    = (float*)d_ws;
    float* hbuf  = ws;                          // 6,400,000 f; ebuf during build (9.6MB), h after last aggemm
    __half* u_a  = (__half*)(ws + 6400000);     // 6.4M halves
    __half* u_b  = (__half*)(ws + 9600000);     // 6.4M halves
    float* dis   = ws + 12800000;               // 100,000 f
    float* sigma = ws + 12900000;               // 100,000 f
    float* Wt    = ws + 13000000;               // 4096 f
    float* bt    = Wt + 4096;                   // 64 f
    float* hg    = bt + 64;                     // 8192 f
    float* sums  = hg + 8192;                   // 640 f (sx,s0,s1,s2)
    int*   cnt   = (int*)(sums + 640);          // 100,000 i
    int*   ecsr  = cnt + 100000;                // 6,400,000 i
    int*   deg   = (int*)u_b;                   // 100,000 i scratch; dead before u_b written
    int*   gcnt  = deg + 100000;                // 16,384 i scratch (u_b region)
    int*   goff  = gcnt + 16384;                // 16,384 i scratch (u_b region)
    long long* ebuf = (long long*)hbuf;         // 1.2M * 8B = 9.6MB; dead before hbuf written

    float* sx = sums;
    float* s0 = sums + 128;
    float* s1 = sums + 256;
    float* s2 = sums + 384;

    const int* srcp = ei;
    const int* dstp = ei + N_EDGES;

    // zero hg + sums + cnt in one contiguous memset; deg lives in u_b scratch
    hipMemsetAsync(hg, 0, (8192 + 640 + 100000) * sizeof(float), stream);
    hipMemsetAsync(deg, 0, 100000 * sizeof(int), stream);

    // deterministic partitioned CSR build: count -> scan -> place -> per-shard scatter
    k_cnt<<<NBLK, 256, 0, stream>>>(srcp, dstp, deg, gcnt);
    k_scan<<<1, 256, 0, stream>>>(gcnt, goff);
    k_place<<<NBLK, 256, 0, stream>>>(srcp, dstp, goff, ebuf);
    k_scat<<<512, 256, 0, stream>>>(ebuf, goff, cnt, ecsr);
    k_dis<<<(N_NODES + 255) / 256, 256, 0, stream>>>(deg, dis);
    k_sigma<<<1024, 256, 0, stream>>>(dis, cnt, ecsr, sigma);

    // feature layer: stats on x -> fold -> GEMM+relu -> u0 (fp16, dis-scaled), stats -> s0
    k_stats<<<512, 256, 0, stream>>>(x, sx);
    k_fold<<<1, 256, 0, stream>>>(sx, bn_feat_g, bn_feat_b, W_feat, b_feat, 1, Wt, bt);
    k_gemm2<<<2048, 256, 0, stream>>>(x, Wt, bt, dis, u_a, s0, 1);

    // 3 GCN conv layers: aggemm with in-kernel BN fold + sigma correction, u double-buffered
    k_aggemm<<<2048, 256, 0, stream>>>(u_a, dis, sigma, cnt, ecsr,
                                       s0, conv_bn_g + 0, conv_bn_b + 0,
                                       conv_W + 0, conv_b + 0,
                                       u_b, nullptr, 0, s1, 1);
    k_aggemm<<<2048, 256, 0, stream>>>(u_b, dis, sigma, cnt, ecsr,
                                       s1, conv_bn_g + 64, conv_bn_b + 64,
                                       conv_W + 4096, conv_b + 64,
                                       u_a, nullptr, 0, s2, 1);
    k_aggemm<<<2048, 256, 0, stream>>>(u_a, dis, sigma, cnt, ecsr,
                                       s2, conv_bn_g + 128, conv_bn_b + 128,
                                       conv_W + 8192, conv_b + 128,
                                       nullptr, hbuf, 1, nullptr, 0);

    // pooling + tail (BN-fc stats computed inside k_tail)
    k_pool<<<4 * GRAPHS, 256, 0, stream>>>(hbuf, batch, hg);
    k_tail<<<1, 512, 0, stream>>>(hg, bn_fc_g, bn_fc_b, W_fc, b_fc,
                                  bn_hid_g, bn_hid_b, W_cls, b_cls, out);
}